// Round 4
// baseline (157.854 us; speedup 1.0000x reference)
//
#include <hip/hip_runtime.h>
#include <hip/hip_bf16.h>

// Problem constants (fixed by setup_inputs)
#define N_ 4
#define M_ 64
#define C_ 768
#define HF 48
#define WF 48
#define HWF (HF*WF)   // 2304
#define HI 768
#define WI 768
#define R_ 8
#define NM (N_*M_)

// ws layout:
//   [0)        uint bbox[NM][4]  (ymin'=max(768-y), ymax'=max(y+1),
//                                 xmin'=max(768-x), xmax'=max(x+1); empty <=> ymax'==0)
//   [4096)     uint8 masks_small[NM][48*48]
//   [1<<20)    float featT[N][HWF][C]  (n,hw,c)   27 MB
// One hipMemsetAsync(0) over [0, 4096 + NM*2304) initializes everything.
#define WS_BBOX_OFF   0
#define WS_MS_OFF     4096
#define WS_FEATT_OFF  (1u<<20)
#define MS_PER_MAP    (HF*WF)   // 2304
#define WS_ZERO_BYTES (WS_MS_OFF + NM*MS_PER_MAP)   // 593920

#define VEC4_PER_MAP  (HI*WI/4)                       // 147456
#define SCAN_LPT      16                              // float4 loads per thread
#define SCAN_BX       (VEC4_PER_MAP/(256*SCAN_LPT))   // 36
#define SCAN_BLOCKS   (NM*SCAN_BX)                    // 9216
#define TRANS_BLOCKS  ((C_/64)*(HWF/64)*N_)           // 12*36*4 = 1728

typedef float f32x4 __attribute__((ext_vector_type(4)));

// Fused: [0, SCAN_BLOCKS) stream the 604MB mask tensor (bbox atomics +
// masks_small idempotent stores); [SCAN_BLOCKS, +TRANS_BLOCKS) transpose
// feat (n,c,hw) -> featT (n,hw,c). Both are HBM-bound and independent, so
// fusing overlaps the transpose under the scan.
//
// Scan math: window(15) < stride(16) => each nonzero pixel maps to at most
// one masks_small cell: i=(y+7)>>4 valid iff (y&15)!=8 && i<48.
__global__ void scan_trans_kernel(const f32x4* __restrict__ masks,
                                  const float* __restrict__ feat,
                                  unsigned int* __restrict__ bbox,
                                  unsigned char* __restrict__ msmall,
                                  float* __restrict__ featT) {
    __shared__ float lds[64][65];
    const int bid = blockIdx.x;
    const int tid = threadIdx.x;

    if (bid < SCAN_BLOCKS) {
        const int nm = bid / SCAN_BX;
        const int bx = bid - nm * SCAN_BX;
        const size_t map_off = (size_t)nm * VEC4_PER_MAP;
        const int chunk = bx * (256 * SCAN_LPT);
        unsigned int* bb = bbox + nm * 4;
        unsigned char* ms = msmall + nm * MS_PER_MAP;

        #pragma unroll
        for (int k = 0; k < SCAN_LPT; ++k) {
            const int t = chunk + k * 256 + tid;
            const f32x4 v = __builtin_nontemporal_load(masks + map_off + t);
            if (v.x > 0.f || v.y > 0.f || v.z > 0.f || v.w > 0.f) {
                const int y  = t / (WI/4);
                const int x4 = (t - y * (WI/4)) * 4;
                const float vv[4] = {v.x, v.y, v.z, v.w};
                #pragma unroll
                for (int q = 0; q < 4; ++q) {
                    if (vv[q] > 0.f) {
                        const int x = x4 + q;
                        atomicMax(&bb[0], (unsigned int)(HI - y));
                        atomicMax(&bb[1], (unsigned int)(y + 1));
                        atomicMax(&bb[2], (unsigned int)(WI - x));
                        atomicMax(&bb[3], (unsigned int)(x + 1));
                        const int i = (y + 7) >> 4;
                        const int j = (x + 7) >> 4;
                        if (((y & 15) != 8) && i < HF && ((x & 15) != 8) && j < WF)
                            ms[i*WF + j] = 1;
                    }
                }
            }
        }
    } else {
        const int tb  = bid - SCAN_BLOCKS;
        const int ct  = tb % (C_/64);
        const int tmp = tb / (C_/64);
        const int hwt = tmp % (HWF/64);
        const int n   = tmp / (HWF/64);
        const int hw0 = hwt * 64;
        const int c0  = ct * 64;
        const int lane = tid & 63;
        const int grp  = tid >> 6;      // 0..3

        #pragma unroll
        for (int i = 0; i < 16; ++i) {
            const int c_l = i * 4 + grp;
            lds[c_l][lane] = __builtin_nontemporal_load(
                feat + ((size_t)(n * C_ + c0 + c_l)) * HWF + hw0 + lane);
        }
        __syncthreads();
        #pragma unroll
        for (int i = 0; i < 16; ++i) {
            const int hw_l = i * 4 + grp;
            featT[((size_t)(n * HWF + hw0 + hw_l)) * C_ + c0 + lane] = lds[lane][hw_l];
        }
    }
}

// Fused boxes + roi_masks + roi-align + mask-multiply.
// Grid (C/64, NM), 256 threads. Each block recomputes the cheap box algebra
// and 8x8 crop; blocks with blockIdx.x==0 write outputs 0 (boxes) and 1
// (roi_masks). Lanes run along c in featT so all bilinear loads are
// coalesced; a 64x65 LDS tile transposes results to coalesced emb stores.
__global__ void roi_fused_kernel(const float* __restrict__ featT,
                                 const unsigned int* __restrict__ bbox,
                                 const unsigned char* __restrict__ msmall,
                                 float* __restrict__ out) {
    const int nm = blockIdx.y;
    const int n  = nm >> 6;
    const int c0 = blockIdx.x * 64;
    const int tid = threadIdx.x;

    __shared__ float s_w[4][64];
    __shared__ int   s_a[4][64];
    __shared__ float s_m[64];
    __shared__ float tile[64][65];

    if (tid < 64) {
        const uint4 bb = ((const uint4*)bbox)[nm];
        float bf0, bf1, bf2, bf3;
        if (bb.y == 0u) {            // empty mask
            bf0 = bf1 = bf2 = bf3 = 0.f;
        } else {
            const int ymin = HI - (int)bb.x, ymax = (int)bb.y - 1;
            const int xmin = WI - (int)bb.z, xmax = (int)bb.w - 1;
            // dilate(+-7) + expand(+-1) + clip == +-8 clipped; /16 exact
            bf0 = (float)max(xmin - 8, 0) * 0.0625f;
            bf1 = (float)max(ymin - 8, 0) * 0.0625f;
            bf2 = (float)min(xmax + 8, WI - 1) * 0.0625f;
            bf3 = (float)min(ymax + 8, HI - 1) * 0.0625f;
        }
        if (blockIdx.x == 0 && tid == 0) {
            out[nm*4+0] = bf0 * (1.f/HF);
            out[nm*4+1] = bf1 * (1.f/HF);
            out[nm*4+2] = bf2 * (1.f/HF);
            out[nm*4+3] = bf3 * (1.f/HF);
        }

        // roi_masks crop (8x8 over masks_small)
        const int x1c = max((int)floorf(bf0), 0);
        const int y1c = max((int)floorf(bf1), 0);
        const int x2c = min((int)floorf(bf2), WF - 1);
        const int y2c = min((int)floorf(bf3), HF - 1);
        const int h = y2c - y1c + 1;
        const int w = x2c - x1c + 1;
        const int r = tid >> 3, s = tid & 7;
        const int yi = y1c + (r * h) / R_;
        const int xi = x1c + (s * w) / R_;
        const float cv = (float)msmall[nm*MS_PER_MAP + yi*WF + xi];
        const float m = __any(cv > 0.f) ? cv : 1.f;
        s_m[tid] = m;
        if (blockIdx.x == 0)
            out[NM*4 + nm*64 + tid] = m;

        // bilinear sample positions/weights (shared across all channels)
        const float bw = fmaxf(bf2 - bf0, 1.f) * (1.f / R_);
        const float bh = fmaxf(bf3 - bf1, 1.f) * (1.f / R_);
        float py = bf1 + ((float)r + 0.5f) * bh;
        float px = bf0 + ((float)s + 0.5f) * bw;
        py = fminf(fmaxf(py, 0.f), (float)(HF - 1));
        px = fminf(fmaxf(px, 0.f), (float)(WF - 1));
        const int y0 = (int)floorf(py);
        const int x0 = (int)floorf(px);
        const int y1i = min(y0 + 1, HF - 1);
        const int x1i = min(x0 + 1, WF - 1);
        const float ly = py - (float)y0, lx = px - (float)x0;
        const float hy = 1.f - ly,       hx = 1.f - lx;
        s_w[0][tid] = hy * hx;  s_w[1][tid] = hy * lx;
        s_w[2][tid] = ly * hx;  s_w[3][tid] = ly * lx;
        s_a[0][tid] = y0 * WF + x0;   s_a[1][tid] = y0 * WF + x1i;
        s_a[2][tid] = y1i * WF + x0;  s_a[3][tid] = y1i * WF + x1i;
    }
    __syncthreads();

    const int c_l = tid & 63;
    const int pg  = tid >> 6;       // 0..3, 16 positions each
    const float* fb = featT + (size_t)n * HWF * C_ + c0 + c_l;
    #pragma unroll
    for (int p = 0; p < 16; ++p) {
        const int pos = pg * 16 + p;
        const float v = s_w[0][pos] * fb[(size_t)s_a[0][pos] * C_]
                      + s_w[1][pos] * fb[(size_t)s_a[1][pos] * C_]
                      + s_w[2][pos] * fb[(size_t)s_a[2][pos] * C_]
                      + s_w[3][pos] * fb[(size_t)s_a[3][pos] * C_];
        tile[pos][c_l] = v;
    }
    __syncthreads();

    float* emb = out + NM*4 + NM*R_*R_;
    const int pos = tid & 63;
    #pragma unroll
    for (int i = 0; i < 16; ++i) {
        const int cc = i * 4 + (tid >> 6);
        emb[((size_t)nm * C_ + c0 + cc) * 64 + pos] = tile[pos][cc] * s_m[pos];
    }
}

extern "C" void kernel_launch(void* const* d_in, const int* in_sizes, int n_in,
                              void* d_out, int out_size, void* d_ws, size_t ws_size,
                              hipStream_t stream) {
    const float* feat  = (const float*)d_in[0];   // (4,768,48,48)
    const float* masks = (const float*)d_in[1];   // (4,64,768,768)
    float* out = (float*)d_out;

    char* ws = (char*)d_ws;
    unsigned int* bbox    = (unsigned int*)(ws + WS_BBOX_OFF);
    unsigned char* msmall = (unsigned char*)(ws + WS_MS_OFF);
    float* featT          = (float*)(ws + WS_FEATT_OFF);

    // init: bbox (all-atomicMax encoding => zeros) + msmall zeros, one memset
    hipMemsetAsync(ws, 0, WS_ZERO_BYTES, stream);

    // phase 1: fused mask scan + feat transpose (both HBM-bound, overlap)
    scan_trans_kernel<<<SCAN_BLOCKS + TRANS_BLOCKS, 256, 0, stream>>>(
        (const f32x4*)masks, feat, bbox, msmall, featT);

    // phase 2: fused boxes + roi_masks + roi-align + emb
    dim3 g2(C_/64, NM);     // (12, 256)
    roi_fused_kernel<<<g2, 256, 0, stream>>>(featT, bbox, msmall, out);
}